// Round 8
// baseline (108.624 us; speedup 1.0000x reference)
//
#include <hip/hip_runtime.h>
#include <hip/hip_bf16.h>

typedef __attribute__((ext_vector_type(8))) short short8;
typedef __attribute__((ext_vector_type(4))) float f32x4;
typedef __attribute__((ext_vector_type(4))) unsigned int u32x4;
typedef unsigned short u16;
typedef unsigned int   u32;
typedef unsigned long long u64;
typedef unsigned char  u8;

#define NN 8192
#define THRESH 0.1f

__device__ __forceinline__ u16 f2bf(float f){
  __hip_bfloat16 h = __float2bfloat16(f);
  u16 u; __builtin_memcpy(&u, &h, 2); return u;
}

// ---- K1: normalize state rows ----
__global__ __launch_bounds__(256) void k_norm(const float* __restrict__ st, float* __restrict__ sn){
  int i = blockIdx.x*256 + threadIdx.x;
  const float4* s4 = reinterpret_cast<const float4*>(st + i*16);
  float4 v[4]; float ss = 0.f;
  #pragma unroll
  for (int q=0;q<4;q++){ v[q]=s4[q]; ss += v[q].x*v[q].x+v[q].y*v[q].y+v[q].z*v[q].z+v[q].w*v[q].w; }
  float inv = 1.0f/(sqrtf(ss) + 1e-12f);
  float4* d4 = reinterpret_cast<float4*>(sn + i*16);
  #pragma unroll
  for (int q=0;q<4;q++){ float4 o; o.x=v[q].x*inv; o.y=v[q].y*inv; o.z=v[q].z*inv; o.w=v[q].w*inv; d4[q]=o; }
}

// ---- K2: symmetric tile mask. Wave-tile = 256 i (4 rows/lane) x 32 j, upper-tri (J0>=I0
// at 32-granularity within/right of I-block). 4224 wave-tiles -> 4.1 waves/SIMD.
// 4 b128 broadcast reads per j shared across 4 i-chunks (LDS pipe halved vs R7). ----
__global__ __launch_bounds__(256) void k_maskT5(const float* __restrict__ sn, u32* __restrict__ maskT){
  __shared__ float sjtA[4*32*20];                // 4 waves x 32 rows x stride 20
  int tid  = threadIdx.x;
  int lane = tid & 63;
  int wid  = tid >> 6;
  int t = __builtin_amdgcn_readfirstlane((int)blockIdx.x*4 + wid);  // 0..4223
  // I-blocks of 256 (k=0..31), j-blocks of 32 starting at 8k. C(k) = 4k(65-k).
  int k = 0;
  while (4*(k+1)*(64-k) <= t) ++k;
  int I0 = __builtin_amdgcn_readfirstlane(k << 8);
  int jb = 8*k + (t - 4*k*(65-k));
  int J0 = __builtin_amdgcn_readfirstlane(jb << 5);

  // stage 32 j-rows (wave-private)
  float* sjt = sjtA + wid*640;
  #pragma unroll
  for (int s=0;s<2;s++){
    int c2 = lane + 64*s;
    int row = c2 >> 2, q = c2 & 3;
    float4 v = *reinterpret_cast<const float4*>(sn + (J0+row)*16 + q*4);
    *reinterpret_cast<float4*>(sjt + row*20 + q*4) = v;
  }

  float si[4][16];
  #pragma unroll
  for (int c=0;c<4;c++){
    #pragma unroll
    for (int q=0;q<4;q++){
      float4 v = reinterpret_cast<const float4*>(sn + (I0 + 64*c + lane)*16)[q];
      si[c][4*q]=v.x; si[c][4*q+1]=v.y; si[c][4*q+2]=v.z; si[c][4*q+3]=v.w;
    }
  }

  u32 roww[4] = {0,0,0,0};       // row-words: 4 i-rows/lane over 32 j-bits
  u32 colw[8] = {0,0,0,0,0,0,0,0}; // col-words (lane j<32): 256 i-bits
  #pragma unroll 2
  for (int j2=0; j2<32; ++j2){
    const float* sp = sjt + j2*20;               // uniform addr -> broadcast b128
    float4 p0 = *reinterpret_cast<const float4*>(sp);
    float4 p1 = *reinterpret_cast<const float4*>(sp+4);
    float4 p2 = *reinterpret_cast<const float4*>(sp+8);
    float4 p3 = *reinterpret_cast<const float4*>(sp+12);
    bool me = (lane == j2);
    #pragma unroll
    for (int c=0;c<4;c++){
      float d0 = p0.x*si[c][0]  + p0.y*si[c][1]  + p0.z*si[c][2]  + p0.w*si[c][3];
      float d1 = p1.x*si[c][4]  + p1.y*si[c][5]  + p1.z*si[c][6]  + p1.w*si[c][7];
      float d2 = p2.x*si[c][8]  + p2.y*si[c][9]  + p2.z*si[c][10] + p2.w*si[c][11];
      float d3 = p3.x*si[c][12] + p3.y*si[c][13] + p3.z*si[c][14] + p3.w*si[c][15];
      float d  = (d0+d1)+(d2+d3);
      bool pr = (d*d >= THRESH);
      u64 bal = __ballot(pr);
      roww[c] |= pr ? (1u<<j2) : 0u;
      colw[2*c]   = me ? (u32)bal       : colw[2*c];
      colw[2*c+1] = me ? (u32)(bal>>32) : colw[2*c+1];
    }
  }

  // self-loop clearing
  #pragma unroll
  for (int c=0;c<4;c++){
    u32 rel = (u32)(I0 + 64*c + lane - J0);
    if (rel < 32u) roww[c] &= ~(1u<<rel);
  }
  u32 off = (u32)(J0 + lane - I0);               // lane<32 meaningful
  #pragma unroll
  for (int w=0;w<8;w++)
    colw[w] &= ~(((off>>5) == (u32)w) ? (1u<<(off&31)) : 0u);

  // stores: row-words (4/lane) + transposed col-words (8, lanes 0-31)
  #pragma unroll
  for (int c=0;c<4;c++)
    maskT[(size_t)jb*NN + I0 + 64*c + lane] = roww[c];
  if (lane < 32){
    #pragma unroll
    for (int w=0;w<8;w++)
      maskT[(size_t)((I0>>5)+w)*NN + J0 + lane] = colw[w];
  }
}

// ---- K2b: deg[i] via popcount; dinv = 1/(deg+eps) ----
__global__ __launch_bounds__(256) void k_deg(const u32* __restrict__ maskT, float* __restrict__ dinvF){
  __shared__ u32 red[256];
  int tid = threadIdx.x;
  int il = tid & 31, ws = tid >> 5;
  int i = blockIdx.x*32 + il;
  u32 s = 0;
  #pragma unroll 8
  for (int w = ws*32; w < ws*32 + 32; ++w) s += __popc(maskT[(size_t)w*NN + i]);
  red[tid] = s;
  __syncthreads();
  if (tid < 32){
    u32 tot = 0;
    #pragma unroll
    for (int g=0; g<8; ++g) tot += red[g*32 + tid];
    dinvF[i] = 1.0f/((float)tot + 1e-6f);
  }
}

// ---- K3: Yt[f][j] = dinv[j] * sum_k X[j,k]*W[f,k]  (bf16, j-contiguous) ----
__global__ __launch_bounds__(128) void k_ygemm(const float* __restrict__ X, const float* __restrict__ W,
                                               const float* __restrict__ dinvF, u16* __restrict__ Yt){
  int tid = threadIdx.x;
  int lane = tid & 63;
  int r = lane & 15, g = lane >> 4;
  int wj = tid >> 6;
  int f0 = blockIdx.x * 32;
  int j0 = blockIdx.y * 128 + wj * 64;
  f32x4 acc[2][4] = {};
  #pragma unroll
  for (int k0 = 0; k0 < 256; k0 += 32){
    short8 a[2], b[4];
    #pragma unroll
    for (int af=0; af<2; af++){
      const float* p = W + (f0 + af*16 + r)*256 + k0 + g*8;
      float4 u = reinterpret_cast<const float4*>(p)[0];
      float4 v = reinterpret_cast<const float4*>(p)[1];
      short8 tt;
      tt[0]=(short)f2bf(u.x); tt[1]=(short)f2bf(u.y); tt[2]=(short)f2bf(u.z); tt[3]=(short)f2bf(u.w);
      tt[4]=(short)f2bf(v.x); tt[5]=(short)f2bf(v.y); tt[6]=(short)f2bf(v.z); tt[7]=(short)f2bf(v.w);
      a[af] = tt;
    }
    #pragma unroll
    for (int bf=0; bf<4; bf++){
      const float* p = X + (j0 + bf*16 + r)*256 + k0 + g*8;
      float4 u = reinterpret_cast<const float4*>(p)[0];
      float4 v = reinterpret_cast<const float4*>(p)[1];
      short8 tt;
      tt[0]=(short)f2bf(u.x); tt[1]=(short)f2bf(u.y); tt[2]=(short)f2bf(u.z); tt[3]=(short)f2bf(u.w);
      tt[4]=(short)f2bf(v.x); tt[5]=(short)f2bf(v.y); tt[6]=(short)f2bf(v.z); tt[7]=(short)f2bf(v.w);
      b[bf] = tt;
    }
    #pragma unroll
    for (int af=0; af<2; af++)
      #pragma unroll
      for (int bf=0; bf<4; bf++)
        acc[af][bf] = __builtin_amdgcn_mfma_f32_16x16x32_bf16(a[af], b[bf], acc[af][bf], 0, 0, 0);
  }
  float ds[4];
  #pragma unroll
  for (int bf=0;bf<4;bf++) ds[bf] = dinvF[j0 + bf*16 + r];
  #pragma unroll
  for (int af=0; af<2; af++)
    #pragma unroll
    for (int bf=0; bf<4; bf++)
      #pragma unroll
      for (int q=0;q<4;q++)
        Yt[(f0 + af*16 + g*4 + q)*NN + j0 + bf*16 + r] = f2bf(acc[af][bf][q] * ds[bf]);
}

// ---- K4: partial[z] = M @ Y. 8-wave block (m128 x n128), 3-buffer depth-2
// global_load_lds pipeline, counted vmcnt(3). 2 blocks/CU x 8 waves = 16 waves/CU. ----
#define VMCNT(N) asm volatile("s_waitcnt vmcnt(" #N ")" ::: "memory")
__global__ __launch_bounds__(512) void k_agg(const u16* __restrict__ Yt, const u32* __restrict__ maskT,
                                             float* __restrict__ part){
  __shared__ u8  ldsB[3][16384];  // [buf][128 n-rows][64 k] bf16, chunk-XOR swizzle via source
  __shared__ u32 ldsM[3][256];    // [buf][row*2 + kword]
  int tid = threadIdx.x;
  int lane = tid & 63, wid = tid >> 6;          // wid 0..7
  int r = lane & 15, g = lane >> 4;
  int wm = wid >> 2, wn = wid & 3;              // wave = m64 x n32
  int p = (int)blockIdx.x + 64*((int)blockIdx.y + 2*(int)blockIdx.z);
  int gq = p & 7, idx = p >> 3;
  int m0 = idx*128;
  int n0 = (gq & 1)*128;
  int zz = gq >> 1;
  int kbase = zz*2048;
  f32x4 acc[4][2] = {};                          // [mf][nf]

  // per-lane global addresses at step T=0
  const char* ytb[2];
  #pragma unroll
  for (int is=0; is<2; ++is){
    int rw = wid*16 + is*8 + (lane>>3);
    ytb[is] = (const char*)(Yt + ((size_t)(n0+rw) << 13) + (size_t)kbase + (size_t)(((lane&7) ^ (rw&7))<<3));
  }
  const char* mkb = (const char*)(maskT + (size_t)((kbase>>5) + (lane&1))*NN + m0 + ((wid*32+lane)>>1));

#define GSTAGE(BUF, T) do { \
    _Pragma("unroll") \
    for (int is=0; is<2; ++is) \
      __builtin_amdgcn_global_load_lds((const __attribute__((address_space(1))) void*)(ytb[is] + (T)*128), \
          (__attribute__((address_space(3))) void*)&ldsB[BUF][wid*2048 + is*1024], 16, 0, 0); \
    if (lane < 32) \
      __builtin_amdgcn_global_load_lds((const __attribute__((address_space(1))) void*)(mkb + (size_t)(T)*65536), \
          (__attribute__((address_space(3))) void*)&ldsM[BUF][wid*32], 4, 0, 0); \
  } while(0)

#define COMPUTE(BUF) do { \
    short8 bfrag[2][2]; \
    _Pragma("unroll") \
    for (int kk=0; kk<2; ++kk) \
      _Pragma("unroll") \
      for (int nf=0; nf<2; ++nf){ \
        int row = wn*32 + nf*16 + r; \
        bfrag[kk][nf] = *reinterpret_cast<const short8*>(&ldsB[BUF][row*128 + (((kk*4+g) ^ (row&7))<<4)]); \
      } \
    __builtin_amdgcn_s_setprio(1); \
    _Pragma("unroll") \
    for (int mf=0; mf<4; ++mf){ \
      u64 mw = *reinterpret_cast<const u64*>(&ldsM[BUF][(wm*64+mf*16+r)*2]); \
      _Pragma("unroll") \
      for (int kk=0; kk<2; ++kk){ \
        u32 byte = ((u32)(mw >> (kk*32)) >> (g*8)) & 0xffu; \
        u32 x = byte * 0x8001u; \
        u32x4 wv; \
        _Pragma("unroll") \
        for (int pp=0; pp<4; ++pp) wv[pp] = ((x >> (2*pp)) & 0x00010001u) * 0x3F80u; \
        short8 a = __builtin_bit_cast(short8, wv); \
        _Pragma("unroll") \
        for (int nf=0; nf<2; ++nf) \
          acc[mf][nf] = __builtin_amdgcn_mfma_f32_16x16x32_bf16(a, bfrag[kk][nf], acc[mf][nf], 0, 0, 0); \
      } \
    } \
    __builtin_amdgcn_s_setprio(0); \
  } while(0)

#define BODY(CB, SB, T) do { \
    GSTAGE(SB, (T)+2); \
    COMPUTE(CB); \
    VMCNT(3); \
    __builtin_amdgcn_s_barrier(); \
  } while(0)

  GSTAGE(0, 0);
  GSTAGE(1, 1);
  VMCNT(3);                       // stage(0) landed; stage(1) in flight
  __builtin_amdgcn_s_barrier();

  #pragma unroll 1
  for (int t = 0; t < 30; t += 3){
    BODY(0, 2, t);
    BODY(1, 0, t+1);
    BODY(2, 1, t+2);
  }
  COMPUTE(0);                     // tile 30
  VMCNT(0);
  __builtin_amdgcn_s_barrier();
  COMPUTE(1);                     // tile 31

#undef GSTAGE
#undef COMPUTE
#undef BODY

  float* dst = part + (size_t)zz * (NN*256);
  #pragma unroll
  for (int mf=0; mf<4; mf++)
    #pragma unroll
    for (int nf=0; nf<2; nf++)
      #pragma unroll
      for (int q=0;q<4;q++){
        int row = m0 + wm*64 + mf*16 + g*4 + q;
        int col = n0 + wn*32 + nf*16 + r;
        dst[row*256 + col] = acc[mf][nf][q];
      }
}

// ---- K5: out = bias + sum_z partial[z] ----
__global__ __launch_bounds__(256) void k_reduce(const float* __restrict__ part, const float* __restrict__ bias,
                                                float* __restrict__ out){
  int i = blockIdx.x*256 + threadIdx.x;
  float4 s0 = reinterpret_cast<const float4*>(part          )[i];
  float4 s1 = reinterpret_cast<const float4*>(part + 2097152)[i];
  float4 s2 = reinterpret_cast<const float4*>(part + 4194304)[i];
  float4 s3 = reinterpret_cast<const float4*>(part + 6291456)[i];
  float4 bb = reinterpret_cast<const float4*>(bias)[i & 63];
  float4 o;
  o.x = s0.x+s1.x+s2.x+s3.x+bb.x;
  o.y = s0.y+s1.y+s2.y+s3.y+bb.y;
  o.z = s0.z+s1.z+s2.z+s3.z+bb.z;
  o.w = s0.w+s1.w+s2.w+s3.w+bb.w;
  reinterpret_cast<float4*>(out)[i] = o;
}

extern "C" void kernel_launch(void* const* d_in, const int* in_sizes, int n_in,
                              void* d_out, int out_size, void* d_ws, size_t ws_size,
                              hipStream_t stream) {
  const float* X    = (const float*)d_in[0];
  const float* S    = (const float*)d_in[1];
  const float* W    = (const float*)d_in[2];
  const float* bias = (const float*)d_in[3];
  float* out = (float*)d_out;
  char* ws = (char*)d_ws;
  u32*   maskT = (u32*)  (ws + 0);         //  8 MiB  [256 jwords][8192 i]
  u16*   Yt    = (u16*)  (ws + 8388608);   //  4 MiB  bf16 [256 f][8192 j]
  float* snorm = (float*)(ws + 12582912);  // 512 KiB
  float* dinvF = (float*)(ws + 13107200);  //  32 KiB
  float* part  = (float*)(ws + 13139968);  //  32 MiB fp32 [4][8192][256]

  k_norm  <<<dim3(32),     dim3(256), 0, stream>>>(S, snorm);
  k_maskT5<<<dim3(1056),   dim3(256), 0, stream>>>(snorm, maskT);
  k_deg   <<<dim3(256),    dim3(256), 0, stream>>>(maskT, dinvF);
  k_ygemm <<<dim3(8,64),   dim3(128), 0, stream>>>(X, W, dinvF, Yt);
  k_agg   <<<dim3(64,2,4), dim3(512), 0, stream>>>(Yt, maskT, part);
  k_reduce<<<dim3(2048),   dim3(256), 0, stream>>>(part, bias, out);
}

// Round 9
// 102.411 us; speedup vs baseline: 1.0607x; 1.0607x over previous
//
#include <hip/hip_runtime.h>
#include <hip/hip_bf16.h>

typedef __attribute__((ext_vector_type(8))) short short8;
typedef __attribute__((ext_vector_type(4))) float f32x4;
typedef __attribute__((ext_vector_type(4))) unsigned int u32x4;
typedef unsigned short u16;
typedef unsigned int   u32;
typedef unsigned long long u64;
typedef unsigned char  u8;

#define NN 8192
#define THRESH 0.1f

__device__ __forceinline__ u16 f2bf(float f){
  __hip_bfloat16 h = __float2bfloat16(f);
  u16 u; __builtin_memcpy(&u, &h, 2); return u;
}
__device__ __forceinline__ float bf2f(u16 h){
  u32 u = ((u32)h) << 16;
  return __builtin_bit_cast(float, u);
}

// ---- K1: normalize state rows ----
__global__ __launch_bounds__(256) void k_norm(const float* __restrict__ st, float* __restrict__ sn){
  int i = blockIdx.x*256 + threadIdx.x;
  const float4* s4 = reinterpret_cast<const float4*>(st + i*16);
  float4 v[4]; float ss = 0.f;
  #pragma unroll
  for (int q=0;q<4;q++){ v[q]=s4[q]; ss += v[q].x*v[q].x+v[q].y*v[q].y+v[q].z*v[q].z+v[q].w*v[q].w; }
  float inv = 1.0f/(sqrtf(ss) + 1e-12f);
  float4* d4 = reinterpret_cast<float4*>(sn + i*16);
  #pragma unroll
  for (int q=0;q<4;q++){ float4 o; o.x=v[q].x*inv; o.y=v[q].y*inv; o.z=v[q].z*inv; o.w=v[q].w*inv; d4[q]=o; }
}

// ---- K2: symmetric tile mask. Wave-tile = 256 i (4 rows/lane) x 32 j, upper-tri. ----
__global__ __launch_bounds__(256) void k_maskT5(const float* __restrict__ sn, u32* __restrict__ maskT){
  __shared__ float sjtA[4*32*20];
  int tid  = threadIdx.x;
  int lane = tid & 63;
  int wid  = tid >> 6;
  int t = __builtin_amdgcn_readfirstlane((int)blockIdx.x*4 + wid);  // 0..4223
  int k = 0;
  while (4*(k+1)*(64-k) <= t) ++k;
  int I0 = __builtin_amdgcn_readfirstlane(k << 8);
  int jb = 8*k + (t - 4*k*(65-k));
  int J0 = __builtin_amdgcn_readfirstlane(jb << 5);

  float* sjt = sjtA + wid*640;
  #pragma unroll
  for (int s=0;s<2;s++){
    int c2 = lane + 64*s;
    int row = c2 >> 2, q = c2 & 3;
    float4 v = *reinterpret_cast<const float4*>(sn + (J0+row)*16 + q*4);
    *reinterpret_cast<float4*>(sjt + row*20 + q*4) = v;
  }

  float si[4][16];
  #pragma unroll
  for (int c=0;c<4;c++){
    #pragma unroll
    for (int q=0;q<4;q++){
      float4 v = reinterpret_cast<const float4*>(sn + (I0 + 64*c + lane)*16)[q];
      si[c][4*q]=v.x; si[c][4*q+1]=v.y; si[c][4*q+2]=v.z; si[c][4*q+3]=v.w;
    }
  }

  u32 roww[4] = {0,0,0,0};
  u32 colw[8] = {0,0,0,0,0,0,0,0};
  #pragma unroll 2
  for (int j2=0; j2<32; ++j2){
    const float* sp = sjt + j2*20;
    float4 p0 = *reinterpret_cast<const float4*>(sp);
    float4 p1 = *reinterpret_cast<const float4*>(sp+4);
    float4 p2 = *reinterpret_cast<const float4*>(sp+8);
    float4 p3 = *reinterpret_cast<const float4*>(sp+12);
    bool me = (lane == j2);
    #pragma unroll
    for (int c=0;c<4;c++){
      float d0 = p0.x*si[c][0]  + p0.y*si[c][1]  + p0.z*si[c][2]  + p0.w*si[c][3];
      float d1 = p1.x*si[c][4]  + p1.y*si[c][5]  + p1.z*si[c][6]  + p1.w*si[c][7];
      float d2 = p2.x*si[c][8]  + p2.y*si[c][9]  + p2.z*si[c][10] + p2.w*si[c][11];
      float d3 = p3.x*si[c][12] + p3.y*si[c][13] + p3.z*si[c][14] + p3.w*si[c][15];
      float d  = (d0+d1)+(d2+d3);
      bool pr = (d*d >= THRESH);
      u64 bal = __ballot(pr);
      roww[c] |= pr ? (1u<<j2) : 0u;
      colw[2*c]   = me ? (u32)bal       : colw[2*c];
      colw[2*c+1] = me ? (u32)(bal>>32) : colw[2*c+1];
    }
  }

  #pragma unroll
  for (int c=0;c<4;c++){
    u32 rel = (u32)(I0 + 64*c + lane - J0);
    if (rel < 32u) roww[c] &= ~(1u<<rel);
  }
  u32 off = (u32)(J0 + lane - I0);
  #pragma unroll
  for (int w=0;w<8;w++)
    colw[w] &= ~(((off>>5) == (u32)w) ? (1u<<(off&31)) : 0u);

  #pragma unroll
  for (int c=0;c<4;c++)
    maskT[(size_t)jb*NN + I0 + 64*c + lane] = roww[c];
  if (lane < 32){
    #pragma unroll
    for (int w=0;w<8;w++)
      maskT[(size_t)((I0>>5)+w)*NN + J0 + lane] = colw[w];
  }
}

// ---- K2b: deg[i] via popcount; dinv = 1/(deg+eps) ----
__global__ __launch_bounds__(256) void k_deg(const u32* __restrict__ maskT, float* __restrict__ dinvF){
  __shared__ u32 red[256];
  int tid = threadIdx.x;
  int il = tid & 31, ws = tid >> 5;
  int i = blockIdx.x*32 + il;
  u32 s = 0;
  #pragma unroll 8
  for (int w = ws*32; w < ws*32 + 32; ++w) s += __popc(maskT[(size_t)w*NN + i]);
  red[tid] = s;
  __syncthreads();
  if (tid < 32){
    u32 tot = 0;
    #pragma unroll
    for (int g=0; g<8; ++g) tot += red[g*32 + tid];
    dinvF[i] = 1.0f/((float)tot + 1e-6f);
  }
}

// ---- K3: Yt[f][j] = dinv[j] * sum_k X[j,k]*W[f,k]  (bf16, j-contiguous) ----
__global__ __launch_bounds__(128) void k_ygemm(const float* __restrict__ X, const float* __restrict__ W,
                                               const float* __restrict__ dinvF, u16* __restrict__ Yt){
  int tid = threadIdx.x;
  int lane = tid & 63;
  int r = lane & 15, g = lane >> 4;
  int wj = tid >> 6;
  int f0 = blockIdx.x * 32;
  int j0 = blockIdx.y * 128 + wj * 64;
  f32x4 acc[2][4] = {};
  #pragma unroll
  for (int k0 = 0; k0 < 256; k0 += 32){
    short8 a[2], b[4];
    #pragma unroll
    for (int af=0; af<2; af++){
      const float* p = W + (f0 + af*16 + r)*256 + k0 + g*8;
      float4 u = reinterpret_cast<const float4*>(p)[0];
      float4 v = reinterpret_cast<const float4*>(p)[1];
      short8 tt;
      tt[0]=(short)f2bf(u.x); tt[1]=(short)f2bf(u.y); tt[2]=(short)f2bf(u.z); tt[3]=(short)f2bf(u.w);
      tt[4]=(short)f2bf(v.x); tt[5]=(short)f2bf(v.y); tt[6]=(short)f2bf(v.z); tt[7]=(short)f2bf(v.w);
      a[af] = tt;
    }
    #pragma unroll
    for (int bf=0; bf<4; bf++){
      const float* p = X + (j0 + bf*16 + r)*256 + k0 + g*8;
      float4 u = reinterpret_cast<const float4*>(p)[0];
      float4 v = reinterpret_cast<const float4*>(p)[1];
      short8 tt;
      tt[0]=(short)f2bf(u.x); tt[1]=(short)f2bf(u.y); tt[2]=(short)f2bf(u.z); tt[3]=(short)f2bf(u.w);
      tt[4]=(short)f2bf(v.x); tt[5]=(short)f2bf(v.y); tt[6]=(short)f2bf(v.z); tt[7]=(short)f2bf(v.w);
      b[bf] = tt;
    }
    #pragma unroll
    for (int af=0; af<2; af++)
      #pragma unroll
      for (int bf=0; bf<4; bf++)
        acc[af][bf] = __builtin_amdgcn_mfma_f32_16x16x32_bf16(a[af], b[bf], acc[af][bf], 0, 0, 0);
  }
  float ds[4];
  #pragma unroll
  for (int bf=0;bf<4;bf++) ds[bf] = dinvF[j0 + bf*16 + r];
  #pragma unroll
  for (int af=0; af<2; af++)
    #pragma unroll
    for (int bf=0; bf<4; bf++)
      #pragma unroll
      for (int q=0;q<4;q++)
        Yt[(f0 + af*16 + g*4 + q)*NN + j0 + bf*16 + r] = f2bf(acc[af][bf][q] * ds[bf]);
}

// ---- K4: partial[z] = M @ Y (bf16 out). Block m256 x n256(full), 8 waves wm2 x wn4,
// wave = m128 x n64 (mf8 amortizes B ds_reads, nf4 amortizes mask expansion).
// z=8, 16 K-steps, 3-buffer counted-vmcnt(5) DMA pipeline, 1 block/CU, zz=XCD. ----
#define VMCNT(N) asm volatile("s_waitcnt vmcnt(" #N ")" ::: "memory")
__global__ __launch_bounds__(512, 2) void k_agg(const u16* __restrict__ Yt, const u32* __restrict__ maskT,
                                                u16* __restrict__ part){
  __shared__ u8  ldsB[3][32768];  // [buf][256 n-rows][64 k] bf16, chunk-XOR swizzle via source
  __shared__ u32 ldsM[3][512];    // [buf][row*2 + kword], 256 m-rows
  int tid = threadIdx.x;
  int lane = tid & 63, wid = tid >> 6;          // wid 0..7
  int r = lane & 15, g = lane >> 4;
  int wm = wid >> 2, wn = wid & 3;              // wave = m128 x n64
  int bid = (int)blockIdx.x;
  int zz = bid & 7;                              // K-slice == XCD (round-robin dispatch)
  int m0 = (bid >> 3) * 256;
  int kbase = zz * 1024;
  f32x4 acc[8][4] = {};

  // per-lane global source addresses at step T=0 (source pre-swizzled for linear LDS dest)
  const char* ytb[4];
  #pragma unroll
  for (int is=0; is<4; ++is){
    int rw = wid*32 + is*8 + (lane>>3);
    ytb[is] = (const char*)(Yt + ((size_t)rw << 13) + (size_t)kbase + (size_t)(((lane&7) ^ (rw&7))<<3));
  }
  const char* mkb = (const char*)(maskT + (size_t)((kbase>>5) + (lane&1))*NN + m0 + wid*32 + (lane>>1));

#define GSTAGE(BUF, T) do { \
    _Pragma("unroll") \
    for (int is=0; is<4; ++is) \
      __builtin_amdgcn_global_load_lds((const __attribute__((address_space(1))) void*)(ytb[is] + (T)*128), \
          (__attribute__((address_space(3))) void*)&ldsB[BUF][wid*4096 + is*1024], 16, 0, 0); \
    __builtin_amdgcn_global_load_lds((const __attribute__((address_space(1))) void*)(mkb + (size_t)(T)*65536), \
        (__attribute__((address_space(3))) void*)&ldsM[BUF][wid*64], 4, 0, 0); \
  } while(0)

#define COMPUTE(BUF) do { \
    short8 bfrag[2][4]; \
    _Pragma("unroll") \
    for (int kk=0; kk<2; ++kk) \
      _Pragma("unroll") \
      for (int nf=0; nf<4; ++nf){ \
        int row = wn*64 + nf*16 + r; \
        bfrag[kk][nf] = *reinterpret_cast<const short8*>(&ldsB[BUF][row*128 + (((kk*4+g) ^ (row&7))<<4)]); \
      } \
    __builtin_amdgcn_s_setprio(1); \
    _Pragma("unroll") \
    for (int mf=0; mf<8; ++mf){ \
      int rowm = wm*128 + mf*16 + r; \
      u64 mw = *reinterpret_cast<const u64*>(&ldsM[BUF][rowm*2]); \
      _Pragma("unroll") \
      for (int kk=0; kk<2; ++kk){ \
        u32 byte = ((u32)(mw >> (kk*32)) >> (g*8)) & 0xffu; \
        u32 x = byte * 0x8001u; \
        u32x4 wv; \
        _Pragma("unroll") \
        for (int pp=0; pp<4; ++pp) wv[pp] = ((x >> (2*pp)) & 0x00010001u) * 0x3F80u; \
        short8 a = __builtin_bit_cast(short8, wv); \
        _Pragma("unroll") \
        for (int nf=0; nf<4; ++nf) \
          acc[mf][nf] = __builtin_amdgcn_mfma_f32_16x16x32_bf16(a, bfrag[kk][nf], acc[mf][nf], 0, 0, 0); \
      } \
    } \
    __builtin_amdgcn_s_setprio(0); \
  } while(0)

#define BODY(CB, SB, T) do { \
    GSTAGE(SB, (T)+2); \
    COMPUTE(CB); \
    VMCNT(5); \
    __builtin_amdgcn_s_barrier(); \
  } while(0)

  GSTAGE(0, 0);
  GSTAGE(1, 1);
  VMCNT(5);                       // stage(0) landed; stage(1) in flight
  __builtin_amdgcn_s_barrier();

  #pragma unroll 1
  for (int t = 0; t < 12; t += 3){
    BODY(0, 2, t);
    BODY(1, 0, t+1);
    BODY(2, 1, t+2);
  }
  BODY(0, 2, 12);                 // stages T=14
  BODY(1, 0, 13);                 // stages T=15
  COMPUTE(2);                     // tile 14
  VMCNT(0);
  __builtin_amdgcn_s_barrier();
  COMPUTE(0);                     // tile 15

#undef GSTAGE
#undef COMPUTE
#undef BODY

  u16* dst = part + (size_t)zz * (NN*256);
  #pragma unroll
  for (int mf=0; mf<8; mf++)
    #pragma unroll
    for (int nf=0; nf<4; nf++)
      #pragma unroll
      for (int q=0;q<4;q++){
        int row = m0 + wm*128 + mf*16 + g*4 + q;
        int col = wn*64 + nf*16 + r;
        dst[row*256 + col] = f2bf(acc[mf][nf][q]);
      }
}

// ---- K5: out = bias + sum_z bf16 partial[z] ----
__global__ __launch_bounds__(256) void k_reduce(const u16* __restrict__ part, const float* __restrict__ bias,
                                                float* __restrict__ out){
  int i = blockIdx.x*256 + threadIdx.x;          // f4 index; 524288 total
  float4 bb = reinterpret_cast<const float4*>(bias)[i & 63];
  float a0 = bb.x, a1 = bb.y, a2 = bb.z, a3 = bb.w;
  #pragma unroll
  for (int z=0; z<8; ++z){
    u64 v = *reinterpret_cast<const u64*>(part + (size_t)z*2097152 + (size_t)i*4);
    a0 += bf2f((u16)(v      ));
    a1 += bf2f((u16)(v >> 16));
    a2 += bf2f((u16)(v >> 32));
    a3 += bf2f((u16)(v >> 48));
  }
  float4 o; o.x=a0; o.y=a1; o.z=a2; o.w=a3;
  reinterpret_cast<float4*>(out)[i] = o;
}

extern "C" void kernel_launch(void* const* d_in, const int* in_sizes, int n_in,
                              void* d_out, int out_size, void* d_ws, size_t ws_size,
                              hipStream_t stream) {
  const float* X    = (const float*)d_in[0];
  const float* S    = (const float*)d_in[1];
  const float* W    = (const float*)d_in[2];
  const float* bias = (const float*)d_in[3];
  float* out = (float*)d_out;
  char* ws = (char*)d_ws;
  u32*   maskT = (u32*)  (ws + 0);         //  8 MiB  [256 jwords][8192 i]
  u16*   Yt    = (u16*)  (ws + 8388608);   //  4 MiB  bf16 [256 f][8192 j]
  float* snorm = (float*)(ws + 12582912);  // 512 KiB
  float* dinvF = (float*)(ws + 13107200);  //  32 KiB
  u16*   part  = (u16*)  (ws + 13139968);  //  32 MiB bf16 [8][8192][256]

  k_norm  <<<dim3(32),   dim3(256), 0, stream>>>(S, snorm);
  k_maskT5<<<dim3(1056), dim3(256), 0, stream>>>(snorm, maskT);
  k_deg   <<<dim3(256),  dim3(256), 0, stream>>>(maskT, dinvF);
  k_ygemm <<<dim3(8,64), dim3(128), 0, stream>>>(X, W, dinvF, Yt);
  k_agg   <<<dim3(256),  dim3(512), 0, stream>>>(Yt, maskT, part);
  k_reduce<<<dim3(2048), dim3(256), 0, stream>>>(part, bias, out);
}